// Round 1
// baseline (134.576 us; speedup 1.0000x reference)
//
#include <hip/hip_runtime.h>

#define NR 4096
#define DDIM 256
#define INVT (1.0f/0.07f)

typedef short short8 __attribute__((ext_vector_type(8)));
typedef float floatx4 __attribute__((ext_vector_type(4)));
typedef unsigned short u16;
typedef unsigned int u32;

__device__ __forceinline__ u16 f2bf(float f){
  u32 u = __float_as_uint(f);
  u32 r = (u + 0x7fffu + ((u >> 16) & 1u)) >> 16;   // RNE
  return (u16)r;
}

// ---------------- convert fp32 -> bf16, zero accumulator region ----------------
__global__ void k_convert(const float* __restrict__ A, const float* __restrict__ B,
                          u16* __restrict__ Abf, u16* __restrict__ Bbf,
                          int* __restrict__ zero_region){
  if (blockIdx.x == 0) zero_region[threadIdx.x] = 0;   // first 1024B of ws
  int t = blockIdx.x * 256 + threadIdx.x;              // 0 .. 524287
  const int Q = (NR * DDIM) / 4;                       // 262144 float4 per tensor
  const float4* src = (t < Q) ? (const float4*)A : (const float4*)B;
  u16* dst = (t < Q) ? Abf : Bbf;
  int idx = (t < Q) ? t : t - Q;
  float4 v = src[idx];
  ushort4 o;
  o.x = f2bf(v.x); o.y = f2bf(v.y); o.z = f2bf(v.z); o.w = f2bf(v.w);
  ((ushort4*)dst)[idx] = o;
}

// ---------------- 128x128-tile bf16 MFMA GEMM with fused row/col softmax stats ----------------
// grid (32,32): blockIdx.y = row block, blockIdx.x = col block. 256 thr = 4 waves (2x2 of 64x64).
__global__ __launch_bounds__(256) void k_gemm_stats(
    const u16* __restrict__ Abf, const u16* __restrict__ Bbf,
    float* __restrict__ rp_max, float* __restrict__ rp_sum,
    float* __restrict__ cp_max, float* __restrict__ cp_sum,
    float* __restrict__ sim_diag, int* __restrict__ hard_idx)
{
  __shared__ uint4 lds[2048];                 // 32KB: A tile 16KB + B tile 16KB
  u16* ldsA = (u16*)lds;                      // [128][64] bf16, XOR-swizzled octets
  u16* ldsB = (u16*)(lds + 1024);
  const int rblk = blockIdx.y, cblk = blockIdx.x;
  const int t = threadIdx.x;
  const int w = t >> 6, lane = t & 63;
  const int wr = w >> 1, wc = w & 1;          // 2x2 wave grid, each 64x64
  const int g = lane >> 4, li = lane & 15;

  floatx4 acc[4][4];
  const floatx4 zz = {0.f, 0.f, 0.f, 0.f};
#pragma unroll
  for (int a = 0; a < 4; ++a)
#pragma unroll
    for (int b = 0; b < 4; ++b) acc[a][b] = zz;

  const int srow = t >> 3, soct = t & 7;      // staging: row, 8-elt octet

  for (int ki = 0; ki < 4; ++ki){             // BK = 64, D = 256
    const int k0 = ki * 64;
    if (ki) __syncthreads();
#pragma unroll
    for (int r = 0; r < 4; ++r){
      int row = r * 32 + srow;
      uint4 va = *(const uint4*)(Abf + (rblk*128 + row)*DDIM + k0 + soct*8);
      uint4 vb = *(const uint4*)(Bbf + (cblk*128 + row)*DDIM + k0 + soct*8);
      int off = row*64 + ((soct ^ (row & 7)) * 8);   // swizzle kills frag-read bank conflicts
      *(uint4*)(ldsA + off) = va;
      *(uint4*)(ldsB + off) = vb;
    }
    __syncthreads();
#pragma unroll
    for (int ks = 0; ks < 2; ++ks){
      short8 af[4], bfr[4];
#pragma unroll
      for (int rf = 0; rf < 4; ++rf){
        int row = wr*64 + rf*16 + li;
        int koct = ks*4 + g;
        af[rf] = *(const short8*)(ldsA + row*64 + ((koct ^ (row & 7)) * 8));
      }
#pragma unroll
      for (int cf = 0; cf < 4; ++cf){
        int row = wc*64 + cf*16 + li;
        int koct = ks*4 + g;
        bfr[cf] = *(const short8*)(ldsB + row*64 + ((koct ^ (row & 7)) * 8));
      }
#pragma unroll
      for (int rf = 0; rf < 4; ++rf)
#pragma unroll
        for (int cf = 0; cf < 4; ++cf)
          acc[rf][cf] = __builtin_amdgcn_mfma_f32_16x16x32_bf16(af[rf], bfr[cf], acc[rf][cf], 0, 0, 0);
    }
  }
  __syncthreads();   // LDS now reusable as reduction scratch

  // scale to post-temperature units
#pragma unroll
  for (int rf = 0; rf < 4; ++rf)
#pragma unroll
    for (int cf = 0; cf < 4; ++cf) acc[rf][cf] *= INVT;

  const bool isdiag = (rblk == cblk);

  float* rm = (float*)lds;        // [128][2] row max per 64-col half
  float* rs = rm + 256;           // [128][2] row sumexp
  float* cm = rs + 256;           // [128][2] col max per 64-row half
  float* cs = cm + 256;
  float* hm = cs + 256;           // [128][2] hard-neg masked max
  int*   hj = (int*)(hm + 256);   // [128][2] hard-neg argmax (block-local col)

  // diagonal sim values (C/D layout: col=li, row=g*4+q within 16x16)
  if (isdiag && wr == wc){
#pragma unroll
    for (int rf = 0; rf < 4; ++rf)
#pragma unroll
      for (int q = 0; q < 4; ++q)
        if (g*4 + q == li) sim_diag[rblk*128 + wr*64 + rf*16 + li] = acc[rf][rf][q];
  }

  // row stats: per (rf,q) reduce over 4 cf regs + 16 lanes (same g group = same row)
#pragma unroll
  for (int rf = 0; rf < 4; ++rf){
#pragma unroll
    for (int q = 0; q < 4; ++q){
      float m = -3.0e38f;
#pragma unroll
      for (int cf = 0; cf < 4; ++cf) m = fmaxf(m, acc[rf][cf][q]);
      for (int s = 1; s < 16; s <<= 1) m = fmaxf(m, __shfl_xor(m, s));
      float sum = 0.f;
#pragma unroll
      for (int cf = 0; cf < 4; ++cf) sum += __expf(acc[rf][cf][q] - m);
      for (int s = 1; s < 16; s <<= 1) sum += __shfl_xor(sum, s);
      if (li == 0){
        int r = wr*64 + rf*16 + g*4 + q;
        rm[r*2 + wc] = m; rs[r*2 + wc] = sum;
      }
    }
  }

  // col stats: per cf reduce over 16 (rf,q) regs + lane groups (xor 16,32 = same li = same col)
#pragma unroll
  for (int cf = 0; cf < 4; ++cf){
    float m = -3.0e38f;
#pragma unroll
    for (int rf = 0; rf < 4; ++rf)
#pragma unroll
      for (int q = 0; q < 4; ++q) m = fmaxf(m, acc[rf][cf][q]);
    for (int s = 16; s < 64; s <<= 1) m = fmaxf(m, __shfl_xor(m, s));
    float sum = 0.f;
#pragma unroll
    for (int rf = 0; rf < 4; ++rf)
#pragma unroll
      for (int q = 0; q < 4; ++q) sum += __expf(acc[rf][cf][q] - m);
    for (int s = 16; s < 64; s <<= 1) sum += __shfl_xor(sum, s);
    if (g == 0){
      int c = wc*64 + cf*16 + li;
      cm[c*2 + wr] = m; cs[c*2 + wr] = sum;
    }
  }

  // hard-negative masked argmax (diagonal tile == the per-batch KxK block)
  if (isdiag){
#pragma unroll
    for (int rf = 0; rf < 4; ++rf){
#pragma unroll
      for (int q = 0; q < 4; ++q){
        int rowb = wr*64 + rf*16 + g*4 + q;
        float m = -3.0e38f; int bj = 0;
#pragma unroll
        for (int cf = 0; cf < 4; ++cf){
          int colb = wc*64 + cf*16 + li;
          float v = (colb == rowb) ? -3.4e38f : acc[rf][cf][q];
          if (v > m){ m = v; bj = colb; }
        }
        for (int s = 1; s < 16; s <<= 1){
          float om = __shfl_xor(m, s);
          int   oj = __shfl_xor(bj, s);
          if (om > m || (om == m && oj < bj)){ m = om; bj = oj; }
        }
        if (li == 0){ hm[rowb*2 + wc] = m; hj[rowb*2 + wc] = bj; }
      }
    }
  }

  __syncthreads();

  if (t < 128){
    float m1 = rm[t*2], m2 = rm[t*2+1], s1 = rs[t*2], s2 = rs[t*2+1];
    float M = fmaxf(m1, m2);
    float S = s1*__expf(m1 - M) + s2*__expf(m2 - M);
    rp_max[cblk*NR + rblk*128 + t] = M;
    rp_sum[cblk*NR + rblk*128 + t] = S;
    m1 = cm[t*2]; m2 = cm[t*2+1]; s1 = cs[t*2]; s2 = cs[t*2+1];
    M = fmaxf(m1, m2);
    S = s1*__expf(m1 - M) + s2*__expf(m2 - M);
    cp_max[rblk*NR + cblk*128 + t] = M;
    cp_sum[rblk*NR + cblk*128 + t] = S;
    if (isdiag){
      float h1 = hm[t*2], h2 = hm[t*2+1]; int j1 = hj[t*2], j2 = hj[t*2+1];
      hard_idx[rblk*128 + t] = (h2 > h1 || (h2 == h1 && j2 < j1)) ? j2 : j1;
    }
  }
}

// ---------------- merge 32 partials per row/col, accumulate losses, flag ambiguous rows ----------------
__global__ void k_merge(const float* __restrict__ rp_max, const float* __restrict__ rp_sum,
                        const float* __restrict__ cp_max, const float* __restrict__ cp_sum,
                        const float* __restrict__ sim_diag,
                        float* __restrict__ accums, int* __restrict__ flag_cnt,
                        int* __restrict__ flag_list)
{
  int i = blockIdx.x*256 + threadIdx.x;      // 16 blocks x 256 = 4096
  float M = -3.0e38f, S = 0.f;
  for (int s = 0; s < 32; ++s){
    float m = rp_max[s*NR + i], sm = rp_sum[s*NR + i];
    if (m > M){ S = S*__expf(M - m) + sm; M = m; }
    else        S += sm*__expf(m - M);
  }
  float d = sim_diag[i];
  float a2b = d - (M + logf(S));
  bool flag = (M - d) < 20.0f;               // 14 sigma of bf16 noise (post-temp)
  float Mc = -3.0e38f, Sc = 0.f;
  for (int s = 0; s < 32; ++s){
    float m = cp_max[s*NR + i], sm = cp_sum[s*NR + i];
    if (m > Mc){ Sc = Sc*__expf(Mc - m) + sm; Mc = m; }
    else         Sc += sm*__expf(m - Mc);
  }
  float b2a = d - (Mc + logf(Sc));
  if (flag){
    int p = atomicAdd(flag_cnt, 1);
    if (p < 64) flag_list[p] = i;
  }
  for (int s = 1; s < 64; s <<= 1){ a2b += __shfl_xor(a2b, s); b2a += __shfl_xor(b2a, s); }
  __shared__ float ra[4], rb[4];
  int w = threadIdx.x >> 6, lane = threadIdx.x & 63;
  if (lane == 0){ ra[w] = a2b; rb[w] = b2a; }
  __syncthreads();
  if (threadIdx.x == 0){
    atomicAdd(&accums[0], ra[0]+ra[1]+ra[2]+ra[3]);
    atomicAdd(&accums[1], rb[0]+rb[1]+rb[2]+rb[3]);
  }
}

// ---------------- triplet loss (fp32 exact distances) ----------------
__global__ void k_triplet(const float* __restrict__ A, const float* __restrict__ B,
                          const int* __restrict__ hard_idx, float* __restrict__ accums)
{
  int t = threadIdx.x, w = t >> 6, lane = t & 63;
  int i = blockIdx.x*4 + w;                 // 1024 blocks x 4 waves
  const float4* a4 = (const float4*)(A + i*DDIM);
  const float4* b4 = (const float4*)(B + i*DDIM);
  int nr = (i & ~127) + hard_idx[i];
  const float4* n4 = (const float4*)(B + nr*DDIM);
  float4 a = a4[lane], b = b4[lane], nv = n4[lane];
  float px = a.x-b.x+1e-6f, py = a.y-b.y+1e-6f, pz = a.z-b.z+1e-6f, pw = a.w-b.w+1e-6f;
  float qx = a.x-nv.x+1e-6f, qy = a.y-nv.y+1e-6f, qz = a.z-nv.z+1e-6f, qw = a.w-nv.w+1e-6f;
  float pd = px*px + py*py + pz*pz + pw*pw;
  float nd = qx*qx + qy*qy + qz*qz + qw*qw;
  for (int s = 1; s < 64; s <<= 1){ pd += __shfl_xor(pd, s); nd += __shfl_xor(nd, s); }
  __shared__ float tb[4];
  if (lane == 0) tb[w] = fmaxf(0.f, sqrtf(pd) - sqrtf(nd) + 0.5f);
  __syncthreads();
  if (t == 0) atomicAdd(&accums[2], tb[0]+tb[1]+tb[2]+tb[3]);
}

// ---------------- exact fp32 re-check of flagged rows (acc precision) ----------------
__global__ void k_fixup(const float* __restrict__ A, const float* __restrict__ B,
                        const int* __restrict__ flag_cnt, const int* __restrict__ flag_list,
                        int* __restrict__ viol)
{
  int n = *flag_cnt; if (n > 64) n = 64;
  int t = threadIdx.x;
  for (int f = 0; f < n; ++f){
    int i = flag_list[f];
    const float4* a4 = (const float4*)(A + i*DDIM);
    const float4* bi = (const float4*)(B + i*DDIM);
    float dd = 0.f;
    for (int k = 0; k < 64; ++k){
      float4 a = a4[k], b = bi[k];
      dd += a.x*b.x + a.y*b.y + a.z*b.z + a.w*b.w;
    }
    if (t < 128){
      int j = blockIdx.x*128 + t;            // 32 blocks x 128 = 4096 cols
      if (j != i){
        const float4* bj = (const float4*)(B + j*DDIM);
        float s = 0.f;
        for (int k = 0; k < 64; ++k){
          float4 a = a4[k], b = bj[k];
          s += a.x*b.x + a.y*b.y + a.z*b.z + a.w*b.w;
        }
        if (s >= dd) atomicAdd(&viol[f], 1);
      }
    }
  }
}

// ---------------- finalize ----------------
__global__ void k_final(const float* __restrict__ accums, const int* __restrict__ flag_cnt,
                        const int* __restrict__ viol, float* __restrict__ out)
{
  int n = *flag_cnt; if (n > 64) n = 64;
  int good = 0;
  for (int f = 0; f < n; ++f) if (viol[f] == 0) ++good;
  float lossA = -accums[0] / 4096.f;
  float lossB = -accums[1] / 4096.f;
  float info = 0.5f*(lossA + lossB);
  float trip = accums[2] / 4096.f;
  out[0] = info + 0.1f*trip;
  out[1] = info;
  out[2] = trip;
  out[3] = (float)good / 4096.f;
}

extern "C" void kernel_launch(void* const* d_in, const int* in_sizes, int n_in,
                              void* d_out, int out_size, void* d_ws, size_t ws_size,
                              hipStream_t stream)
{
  const float* A = (const float*)d_in[0];
  const float* B = (const float*)d_in[1];
  float* out = (float*)d_out;
  char* ws = (char*)d_ws;

  // ws layout (~6.3 MB total)
  float* accums    = (float*)ws;                        // [0]=sum_a2b [1]=sum_b2a [2]=sum_trip
  int*   flag_cnt  = (int*)(ws + 12);
  int*   viol      = (int*)(ws + 16);                   // 64 ints
  int*   flag_list = (int*)(ws + 288);                  // 64 ints
  u16*   Abf       = (u16*)(ws + 1024);                 // 2 MB
  u16*   Bbf       = Abf + NR*DDIM;                     // 2 MB
  float* rp_max    = (float*)(ws + 1024 + 2*NR*DDIM*sizeof(u16));
  float* rp_sum    = rp_max + 32*NR;
  float* cp_max    = rp_sum + 32*NR;
  float* cp_sum    = cp_max + 32*NR;
  float* sim_diag  = cp_sum + 32*NR;
  int*   hard_idx  = (int*)(sim_diag + NR);

  k_convert<<<2048, 256, 0, stream>>>(A, B, Abf, Bbf, (int*)ws);
  k_gemm_stats<<<dim3(32, 32), 256, 0, stream>>>(Abf, Bbf, rp_max, rp_sum,
                                                 cp_max, cp_sum, sim_diag, hard_idx);
  k_merge<<<16, 256, 0, stream>>>(rp_max, rp_sum, cp_max, cp_sum, sim_diag,
                                  accums, flag_cnt, flag_list);
  k_triplet<<<1024, 256, 0, stream>>>(A, B, hard_idx, accums);
  k_fixup<<<32, 256, 0, stream>>>(A, B, flag_cnt, flag_list, viol);
  k_final<<<1, 1, 0, stream>>>(accums, flag_cnt, viol, out);
}

// Round 2
// 109.882 us; speedup vs baseline: 1.2247x; 1.2247x over previous
//
#include <hip/hip_runtime.h>

#define NR 4096
#define DDIM 256
#define INVT (1.0f/0.07f)

typedef short short8 __attribute__((ext_vector_type(8)));
typedef float floatx4 __attribute__((ext_vector_type(4)));
typedef unsigned short u16;
typedef unsigned int u32;

__device__ __forceinline__ u16 f2bf(float f){
  u32 u = __float_as_uint(f);
  return (u16)((u + 0x7fffu + ((u >> 16) & 1u)) >> 16);   // RNE
}

__device__ __forceinline__ void async_copy16(const u16* g, u16* l){
  __builtin_amdgcn_global_load_lds(
      (const __attribute__((address_space(1))) void*)g,
      (__attribute__((address_space(3))) void*)l, 16, 0, 0);
}

// ---------------- convert fp32 -> bf16, zero accumulator region ----------------
__global__ void k_convert(const float* __restrict__ A, const float* __restrict__ B,
                          u16* __restrict__ Abf, u16* __restrict__ Bbf,
                          int* __restrict__ zero_region){
  if (blockIdx.x == 0) zero_region[threadIdx.x] = 0;   // first 1024B of ws
  int t = blockIdx.x * 256 + threadIdx.x;
  const int Q = (NR * DDIM) / 4;
  const float4* src = (t < Q) ? (const float4*)A : (const float4*)B;
  u16* dst = (t < Q) ? Abf : Bbf;
  int idx = (t < Q) ? t : t - Q;
  float4 v = src[idx];
  ushort4 o;
  o.x = f2bf(v.x); o.y = f2bf(v.y); o.z = f2bf(v.z); o.w = f2bf(v.w);
  ((ushort4*)dst)[idx] = o;
}

// ---------------- 128x128-tile bf16 MFMA GEMM with fused row/col softmax stats ----------------
// 1D grid of 1024 blocks, XCD-swizzled. 256 thr = 4 waves (2x2 of 64x64).
// LDS tile layout: row-major [128][64] bf16, physical octet p of row r holds
// logical octet p ^ (r&7) (permutation applied at the GLOBAL address so
// global_load_lds's lane-ordered store lands swizzled; frag ds_read_b128 is
// then 2-way-conflict max = free).
__global__ __launch_bounds__(256) void k_gemm_stats(
    const u16* __restrict__ Abf, const u16* __restrict__ Bbf,
    float* __restrict__ rp_max, float* __restrict__ rp_sum,
    float* __restrict__ cp_max, float* __restrict__ cp_sum,
    float* __restrict__ sim_diag, int* __restrict__ hard_idx)
{
  __shared__ u16 ldsA[128*64];
  __shared__ u16 ldsB[128*64];

  const int bid = blockIdx.x;
  const int xc = bid & 7, qv = bid >> 3;
  const int rblk = (qv >> 5)*8 + xc;      // each XCD: 4 rblk x 32 cblk band
  const int cblk = qv & 31;

  const int t = threadIdx.x;
  const int w = t >> 6, lane = t & 63;
  const int wr = w >> 1, wc = w & 1;
  const int g = lane >> 4, li = lane & 15;

  floatx4 acc[4][4];
  const floatx4 zz = {0.f,0.f,0.f,0.f};
#pragma unroll
  for (int a = 0; a < 4; ++a)
#pragma unroll
    for (int b = 0; b < 4; ++b) acc[a][b] = zz;

  const int lrow = lane >> 3;             // row within 8-row chunk
  const int olog = (lane & 7) ^ lrow;     // permuted source octet
  const u16* baseA = Abf + rblk*128*DDIM;
  const u16* baseB = Bbf + cblk*128*DDIM;

  for (int ki = 0; ki < 4; ++ki){         // BK = 64, D = 256
    if (ki) __syncthreads();
    const int k0 = ki*64;
#pragma unroll
    for (int j = 0; j < 4; ++j){
      int c = w*4 + j;                    // chunk 0..15 (8 rows each)
      int r = c*8 + lrow;
      async_copy16(baseA + r*DDIM + k0 + olog*8, ldsA + c*512);
      async_copy16(baseB + r*DDIM + k0 + olog*8, ldsB + c*512);
    }
    __syncthreads();                      // drains vmcnt then barrier
#pragma unroll
    for (int ks = 0; ks < 2; ++ks){
      short8 af[4], bfr[4];
      const int o = ks*4 + g;
      const int p8 = (o ^ (li & 7)) * 8;
#pragma unroll
      for (int rf = 0; rf < 4; ++rf)
        af[rf] = *(const short8*)(ldsA + (wr*64 + rf*16 + li)*64 + p8);
#pragma unroll
      for (int cf = 0; cf < 4; ++cf)
        bfr[cf] = *(const short8*)(ldsB + (wc*64 + cf*16 + li)*64 + p8);
#pragma unroll
      for (int rf = 0; rf < 4; ++rf)
#pragma unroll
        for (int cf = 0; cf < 4; ++cf)
          acc[rf][cf] = __builtin_amdgcn_mfma_f32_16x16x32_bf16(af[rf], bfr[cf], acc[rf][cf], 0, 0, 0);
    }
  }
  __syncthreads();   // LDS now reusable as reduction scratch

#pragma unroll
  for (int rf = 0; rf < 4; ++rf)
#pragma unroll
    for (int cf = 0; cf < 4; ++cf) acc[rf][cf] *= INVT;

  const bool isdiag = (rblk == cblk);

  float* rm = (float*)ldsA;
  float* rs = rm + 256;
  float* cm = rs + 256;
  float* cs = cm + 256;
  float* hm = cs + 256;
  int*   hj = (int*)(hm + 256);

  // ---- col stats: 4 chains, phased shuffles ----
  {
    float cmv[4], csv[4];
#pragma unroll
    for (int cf = 0; cf < 4; ++cf){
      float m = -3.0e38f;
#pragma unroll
      for (int rf = 0; rf < 4; ++rf)
#pragma unroll
        for (int q = 0; q < 4; ++q) m = fmaxf(m, acc[rf][cf][q]);
      cmv[cf] = m;
    }
#pragma unroll
    for (int s = 16; s < 64; s <<= 1)
#pragma unroll
      for (int cf = 0; cf < 4; ++cf) cmv[cf] = fmaxf(cmv[cf], __shfl_xor(cmv[cf], s));
#pragma unroll
    for (int cf = 0; cf < 4; ++cf){
      float sum = 0.f;
#pragma unroll
      for (int rf = 0; rf < 4; ++rf)
#pragma unroll
        for (int q = 0; q < 4; ++q) sum += __expf(acc[rf][cf][q] - cmv[cf]);
      csv[cf] = sum;
    }
#pragma unroll
    for (int s = 16; s < 64; s <<= 1)
#pragma unroll
      for (int cf = 0; cf < 4; ++cf) csv[cf] += __shfl_xor(csv[cf], s);
    if (g == 0){
#pragma unroll
      for (int cf = 0; cf < 4; ++cf){
        int c = wc*64 + cf*16 + li;
        cm[c*2 + wr] = cmv[cf]; cs[c*2 + wr] = csv[cf];
      }
    }
  }

  // ---- diagonal tile: sim[i,i] + hard-negative masked argmax (phased) ----
  if (isdiag){
    if (wr == wc){
#pragma unroll
      for (int rf = 0; rf < 4; ++rf)
#pragma unroll
        for (int q = 0; q < 4; ++q)
          if (g*4 + q == li) sim_diag[rblk*128 + wr*64 + rf*16 + li] = acc[rf][rf][q];
    }
    float hmv[16]; int hjv[16];
#pragma unroll
    for (int rf = 0; rf < 4; ++rf)
#pragma unroll
      for (int q = 0; q < 4; ++q){
        int rowb = wr*64 + rf*16 + g*4 + q;
        float m = -3.0e38f; int bj = 0;
#pragma unroll
        for (int cf = 0; cf < 4; ++cf){
          int colb = wc*64 + cf*16 + li;
          float v = (colb == rowb) ? -3.4e38f : acc[rf][cf][q];
          if (v > m){ m = v; bj = colb; }
        }
        hmv[rf*4+q] = m; hjv[rf*4+q] = bj;
      }
#pragma unroll
    for (int s = 1; s < 16; s <<= 1)
#pragma unroll
      for (int i = 0; i < 16; ++i){
        float om = __shfl_xor(hmv[i], s);
        int   oj = __shfl_xor(hjv[i], s);
        if (om > hmv[i] || (om == hmv[i] && oj < hjv[i])){ hmv[i] = om; hjv[i] = oj; }
      }
    if (li == 0){
#pragma unroll
      for (int rf = 0; rf < 4; ++rf)
#pragma unroll
        for (int q = 0; q < 4; ++q){
          int rowb = wr*64 + rf*16 + g*4 + q;
          hm[rowb*2 + wc] = hmv[rf*4+q]; hj[rowb*2 + wc] = hjv[rf*4+q];
        }
    }
  }

  // ---- row stats: 16 chains, phased shuffles (forced ILP) ----
  {
    float m16[16];
#pragma unroll
    for (int rf = 0; rf < 4; ++rf)
#pragma unroll
      for (int q = 0; q < 4; ++q){
        float m = -3.0e38f;
#pragma unroll
        for (int cf = 0; cf < 4; ++cf) m = fmaxf(m, acc[rf][cf][q]);
        m16[rf*4+q] = m;
      }
#pragma unroll
    for (int s = 1; s < 16; s <<= 1)
#pragma unroll
      for (int i = 0; i < 16; ++i) m16[i] = fmaxf(m16[i], __shfl_xor(m16[i], s));
    float s16v[16];
#pragma unroll
    for (int rf = 0; rf < 4; ++rf)
#pragma unroll
      for (int q = 0; q < 4; ++q){
        float sum = 0.f;
#pragma unroll
        for (int cf = 0; cf < 4; ++cf) sum += __expf(acc[rf][cf][q] - m16[rf*4+q]);
        s16v[rf*4+q] = sum;
      }
#pragma unroll
    for (int s = 1; s < 16; s <<= 1)
#pragma unroll
      for (int i = 0; i < 16; ++i) s16v[i] += __shfl_xor(s16v[i], s);
    if (li == 0){
#pragma unroll
      for (int rf = 0; rf < 4; ++rf)
#pragma unroll
        for (int q = 0; q < 4; ++q){
          int r = wr*64 + rf*16 + g*4 + q;
          rm[r*2 + wc] = m16[rf*4+q]; rs[r*2 + wc] = s16v[rf*4+q];
        }
    }
  }

  __syncthreads();

  if (t < 128){
    float m1 = rm[t*2], m2 = rm[t*2+1], s1 = rs[t*2], s2 = rs[t*2+1];
    float M = fmaxf(m1, m2);
    float S = s1*__expf(m1 - M) + s2*__expf(m2 - M);
    rp_max[cblk*NR + rblk*128 + t] = M;
    rp_sum[cblk*NR + rblk*128 + t] = S;
    m1 = cm[t*2]; m2 = cm[t*2+1]; s1 = cs[t*2]; s2 = cs[t*2+1];
    M = fmaxf(m1, m2);
    S = s1*__expf(m1 - M) + s2*__expf(m2 - M);
    cp_max[rblk*NR + cblk*128 + t] = M;
    cp_sum[rblk*NR + cblk*128 + t] = S;
    if (isdiag){
      float h1 = hm[t*2], h2 = hm[t*2+1]; int j1 = hj[t*2], j2 = hj[t*2+1];
      hard_idx[rblk*128 + t] = (h2 > h1 || (h2 == h1 && j2 < j1)) ? j2 : j1;
    }
  }
}

// ---------------- merge (blocks 0..15, loads fully unrolled) + triplet (blocks 16..1039) ----------------
__global__ __launch_bounds__(256) void k_merge_triplet(
    const float* __restrict__ rp_max, const float* __restrict__ rp_sum,
    const float* __restrict__ cp_max, const float* __restrict__ cp_sum,
    const float* __restrict__ sim_diag, const float* __restrict__ A,
    const float* __restrict__ B, const int* __restrict__ hard_idx,
    float* __restrict__ accums, int* __restrict__ flag_cnt, int* __restrict__ flag_list)
{
  __shared__ float sred[8];
  const int b = blockIdx.x;
  const int t = threadIdx.x, w = t >> 6, lane = t & 63;
  if (b < 16){
    int i = b*256 + t;
    float mv[32], sv[32];
#pragma unroll
    for (int s = 0; s < 32; ++s) mv[s] = rp_max[s*NR + i];
    float M = mv[0];
#pragma unroll
    for (int s = 1; s < 32; ++s) M = fmaxf(M, mv[s]);
#pragma unroll
    for (int s = 0; s < 32; ++s) sv[s] = rp_sum[s*NR + i];
    float S = 0.f;
#pragma unroll
    for (int s = 0; s < 32; ++s) S += sv[s]*__expf(mv[s] - M);
    float d = sim_diag[i];
    float a2b = d - (M + __logf(S));
    bool flag = (M - d) < 20.0f;             // ~14 sigma of bf16 noise post-temp
#pragma unroll
    for (int s = 0; s < 32; ++s) mv[s] = cp_max[s*NR + i];
    float Mc = mv[0];
#pragma unroll
    for (int s = 1; s < 32; ++s) Mc = fmaxf(Mc, mv[s]);
#pragma unroll
    for (int s = 0; s < 32; ++s) sv[s] = cp_sum[s*NR + i];
    float Sc = 0.f;
#pragma unroll
    for (int s = 0; s < 32; ++s) Sc += sv[s]*__expf(mv[s] - Mc);
    float b2a = d - (Mc + __logf(Sc));
    if (flag){
      int p = atomicAdd(flag_cnt, 1);
      if (p < 64) flag_list[p] = i;
    }
    for (int s = 1; s < 64; s <<= 1){ a2b += __shfl_xor(a2b, s); b2a += __shfl_xor(b2a, s); }
    if (lane == 0){ sred[w] = a2b; sred[4 + w] = b2a; }
    __syncthreads();
    if (t == 0){
      atomicAdd(&accums[0], sred[0]+sred[1]+sred[2]+sred[3]);
      atomicAdd(&accums[1], sred[4]+sred[5]+sred[6]+sred[7]);
    }
  } else {
    int i = (b - 16)*4 + w;
    const float4* a4 = (const float4*)(A + i*DDIM);
    const float4* b4 = (const float4*)(B + i*DDIM);
    int nr = (i & ~127) + hard_idx[i];
    const float4* n4 = (const float4*)(B + nr*DDIM);
    float4 a = a4[lane], bb = b4[lane], nv = n4[lane];
    float px = a.x-bb.x+1e-6f, py = a.y-bb.y+1e-6f, pz = a.z-bb.z+1e-6f, pw = a.w-bb.w+1e-6f;
    float qx = a.x-nv.x+1e-6f, qy = a.y-nv.y+1e-6f, qz = a.z-nv.z+1e-6f, qw = a.w-nv.w+1e-6f;
    float pd = px*px + py*py + pz*pz + pw*pw;
    float nd = qx*qx + qy*qy + qz*qz + qw*qw;
    for (int s = 1; s < 64; s <<= 1){ pd += __shfl_xor(pd, s); nd += __shfl_xor(nd, s); }
    if (lane == 0) sred[w] = fmaxf(0.f, sqrtf(pd) - sqrtf(nd) + 0.5f);
    __syncthreads();
    if (t == 0) atomicAdd(&accums[2], sred[0]+sred[1]+sred[2]+sred[3]);
  }
}

// ---------------- fixup (exact fp32 argmax recheck of flagged rows) + finalize, one block ----------------
__global__ void k_final(const float* __restrict__ A, const float* __restrict__ B,
                        const float* __restrict__ accums, const int* __restrict__ flag_cnt,
                        const int* __restrict__ flag_list, float* __restrict__ out)
{
  __shared__ int sbad;
  const int t = threadIdx.x;
  int n = *flag_cnt; if (n > 64) n = 64;
  int good = 0;
  for (int f = 0; f < n; ++f){
    int i = flag_list[f];
    if (t == 0) sbad = 0;
    __syncthreads();
    const float4* a4 = (const float4*)(A + i*DDIM);
    const float4* bi = (const float4*)(B + i*DDIM);
    float d = 0.f;
    for (int k = 0; k < 64; ++k){
      float4 a = a4[k], bv = bi[k];
      d += a.x*bv.x + a.y*bv.y + a.z*bv.z + a.w*bv.w;
    }
    int v = 0;
    for (int j = t; j < NR; j += 256){
      if (j == i) continue;
      const float4* bj = (const float4*)(B + j*DDIM);
      float s = 0.f;
      for (int k = 0; k < 64; ++k){
        float4 a = a4[k], bv = bj[k];
        s += a.x*bv.x + a.y*bv.y + a.z*bv.z + a.w*bv.w;
      }
      if (s >= d) v = 1;
    }
    if (v) atomicAdd(&sbad, 1);
    __syncthreads();
    if (sbad == 0) ++good;
    __syncthreads();
  }
  if (t == 0){
    float lossA = -accums[0] / 4096.f;
    float lossB = -accums[1] / 4096.f;
    float info = 0.5f*(lossA + lossB);
    float trip = accums[2] / 4096.f;
    out[0] = info + 0.1f*trip;
    out[1] = info;
    out[2] = trip;
    out[3] = (float)good / 4096.f;
  }
}

extern "C" void kernel_launch(void* const* d_in, const int* in_sizes, int n_in,
                              void* d_out, int out_size, void* d_ws, size_t ws_size,
                              hipStream_t stream)
{
  const float* A = (const float*)d_in[0];
  const float* B = (const float*)d_in[1];
  float* out = (float*)d_out;
  char* ws = (char*)d_ws;

  float* accums    = (float*)ws;                        // [0]=sum_a2b [1]=sum_b2a [2]=sum_trip
  int*   flag_cnt  = (int*)(ws + 12);
  int*   flag_list = (int*)(ws + 16);                   // 64 ints
  u16*   Abf       = (u16*)(ws + 1024);                 // 2 MB
  u16*   Bbf       = Abf + NR*DDIM;                     // 2 MB
  float* rp_max    = (float*)(ws + 1024 + 2*NR*DDIM*sizeof(u16));
  float* rp_sum    = rp_max + 32*NR;
  float* cp_max    = rp_sum + 32*NR;
  float* cp_sum    = cp_max + 32*NR;
  float* sim_diag  = cp_sum + 32*NR;
  int*   hard_idx  = (int*)(sim_diag + NR);

  k_convert<<<2048, 256, 0, stream>>>(A, B, Abf, Bbf, (int*)ws);
  k_gemm_stats<<<1024, 256, 0, stream>>>(Abf, Bbf, rp_max, rp_sum,
                                         cp_max, cp_sum, sim_diag, hard_idx);
  k_merge_triplet<<<1040, 256, 0, stream>>>(rp_max, rp_sum, cp_max, cp_sum, sim_diag,
                                            A, B, hard_idx, accums, flag_cnt, flag_list);
  k_final<<<1, 256, 0, stream>>>(A, B, accums, flag_cnt, flag_list, out);
}